// Round 6
// baseline (1176.809 us; speedup 1.0000x reference)
//
#include <hip/hip_runtime.h>
#include <hip/hip_bf16.h>
#include <math.h>

#define D_IN  768
#define NHD   8
#define HDIM  96
#define HID   768
#define UPD   1536
#define FUSED 2320
#define KER   4
#define CS    64
#define NCH   64
#define SB    4096
#define BB    2
#define NROW  (BB*SB)          // 8192
#define NCHUNK (BB*NHD*NCH)    // 1024
#define KSCALE 0.10206207261596577f

using u16   = unsigned short;
using frag8 = __attribute__((ext_vector_type(8))) short;
using f32x4 = __attribute__((ext_vector_type(4))) float;

// ---- workspace offsets (floats). peak use 64,684,032 fl <= 65,404,928 cap ----
// weights: wup [H|M 2304x768, L 1536x768], wfus [H|M 3200x1536, L 2432x1536]
#define O_WUP    0            // 2,359,296 fl
#define O_WWO    2359296      // 1,179,648
#define O_WDOWN  3538944      //   589,824
#define O_WFUS   4128768      // 6,782,976
#define O_RT     10911744     // 6,291,456
#define O_XSKIP  17203200     // 6,291,456
#define O_LF     23494656
#define O_IC     23560192
#define O_WC     23625728
#define O_NC     23691264     // 98,304
#define O_XN     23789568     // xn HML 9,437,184 (dead after up GEMM)
#define O_XT     33226752     // xt fp32 12,582,912 (dead after conv)
#define O_XTS    45809664     // xtHM 12.58M -> xcHML 18.87M -> Cc+h
#define O_PROJ   23789568     // proj 19,005,440 over dead xn+xt (live thru attn)
#define O_CC     45809664     // Cc 9,437,184 over dead xc planes
#define O_H      55246848     // h 6,291,456
#define O_OUT1   39518208     // out1 HM 6,291,456 fl, ends exactly at O_XTS

__device__ __forceinline__ void gld_lds16u(const u16* g, u16* l) {
    __builtin_amdgcn_global_load_lds(
        (const __attribute__((address_space(1))) void*)g,
        (__attribute__((address_space(3))) void*)l, 16, 0, 0);
}

// split fp32 -> bf16 hi (RNE) + mid (trunc) + lo (trunc); residual ~2^-25
__device__ __forceinline__ void split3u(float f, unsigned &H, unsigned &M, unsigned &L) {
    unsigned u = __float_as_uint(f);
    unsigned hr = (u + 0x7fffu + ((u >> 16) & 1u)) & 0xffff0000u;
    H = hr;
    float rm = f - __uint_as_float(hr);
    unsigned mr = __float_as_uint(rm) & 0xffff0000u;
    M = mr;
    float rl = rm - __uint_as_float(mr);
    L = __float_as_uint(rl) & 0xffff0000u;
}

// ---------------- weight transpose + 3-way bf16 split ----------------------
__global__ __launch_bounds__(256) void tpose_split(
    const float* __restrict__ w, u16* __restrict__ tH, u16* __restrict__ tM,
    u16* __restrict__ tL, int K, int N)
{
    __shared__ float tile[64][65];
    int k0 = blockIdx.x * 64, n0 = blockIdx.y * 64;
    int t = threadIdx.x;
    int c = t & 63, r4 = t >> 6;
    #pragma unroll
    for (int it = 0; it < 16; ++it) {
        int r = r4 + it * 4;
        int n = n0 + c;
        tile[r][c] = (n < N) ? w[(size_t)(k0 + r) * N + n] : 0.f;
    }
    __syncthreads();
    #pragma unroll
    for (int it = 0; it < 16; ++it) {
        int nn = r4 + it * 4;
        float v = tile[c][nn];
        unsigned H, M, L;
        split3u(v, H, M, L);
        size_t idx = (size_t)(n0 + nn) * K + k0 + c;
        tH[idx] = (u16)(H >> 16);
        tM[idx] = (u16)(M >> 16);
        if (tL) tL[idx] = (u16)(L >> 16);
    }
}

// ---------------- LayerNorm over D_IN -> split planes ----------------------
__global__ __launch_bounds__(256) void ln_in_split(
    const float* __restrict__ x, const float* __restrict__ w,
    const float* __restrict__ b, u16* __restrict__ oH,
    u16* __restrict__ oM, u16* __restrict__ oL)
{
    int row = blockIdx.x;
    size_t base = (size_t)row * D_IN;
    int c0 = threadIdx.x, c1 = threadIdx.x + 256, c2 = threadIdx.x + 512;
    float v0 = x[base + c0], v1 = x[base + c1], v2 = x[base + c2];
    float s = v0 + v1 + v2;
    float ss = v0*v0 + v1*v1 + v2*v2;
    for (int off = 32; off; off >>= 1) { s += __shfl_xor(s, off); ss += __shfl_xor(ss, off); }
    __shared__ float red[8];
    int wid = threadIdx.x >> 6;
    if ((threadIdx.x & 63) == 0) { red[wid] = s; red[4 + wid] = ss; }
    __syncthreads();
    s = red[0] + red[1] + red[2] + red[3];
    ss = red[4] + red[5] + red[6] + red[7];
    float mean = s * (1.f / D_IN);
    float var = ss * (1.f / D_IN) - mean * mean;
    float inv = rsqrtf(var + 1e-6f);
    float r0 = (v0 - mean) * inv * w[c0] + b[c0];
    float r1 = (v1 - mean) * inv * w[c1] + b[c1];
    float r2 = (v2 - mean) * inv * w[c2] + b[c2];
    unsigned H, M, L;
    split3u(r0, H, M, L); oH[base+c0]=(u16)(H>>16); oM[base+c0]=(u16)(M>>16); oL[base+c0]=(u16)(L>>16);
    split3u(r1, H, M, L); oH[base+c1]=(u16)(H>>16); oM[base+c1]=(u16)(M>>16); oL[base+c1]=(u16)(L>>16);
    split3u(r2, H, M, L); oH[base+c2]=(u16)(H>>16); oM[base+c2]=(u16)(M>>16); oL[base+c2]=(u16)(L>>16);
}

// ---------------- MFMA GEMM, pre-split planes, 2-phase dbuf pipeline -------
// R2 schedule verbatim (monolithic compute, counted vmcnt, 2 barriers/step).
// Column-merged: region1 = cols [0,N1) -> C (stride ldC, bias, act, resid,
// optional H/M split); cols [N1,NP1) = pad (skipped); region2 = cols
// [NP1,NP1+768) -> C2 (stride 768, bias2), always 3-term. Block-uniform
// lact = (NT==6 && n0 < NP1) selects 6-term + L staging; region2 blocks run
// the exact standalone-NT3 MFMA sequence -> bit-identical outputs.
template<int NT, int NTH>
__global__ __launch_bounds__(NTH) void gemm_sp(
    const u16* __restrict__ aH, const u16* __restrict__ aM, const u16* __restrict__ aL,
    const u16* __restrict__ bH, const u16* __restrict__ bM, const u16* __restrict__ bL,
    const float* __restrict__ bias, const float* __restrict__ resid,
    float* __restrict__ C, u16* __restrict__ cH, u16* __restrict__ cM,
    int ldC, int N1, int NP1, float* __restrict__ C2, const float* __restrict__ bias2,
    int K, int act)
{
    constexpr int BM = (NT == 6) ? 256 : 128;
    __shared__ u16 AHM[2][BM * 64];
    __shared__ u16 BHM[2][128 * 64];
    __shared__ u16 ALp[(NT == 6) ? 2 : 1][(NT == 6) ? 128 * 64 : 8];
    __shared__ u16 BLp[(NT == 6) ? 2 : 1][(NT == 6) ? 64 * 64 : 8];

    int t = threadIdx.x;
    int wave = t >> 6, lane = t & 63;
    // XCD-aware bijective swizzle (all grids are multiples of 8)
    int lin = blockIdx.y * gridDim.x + blockIdx.x;
    int cpx = (gridDim.x * gridDim.y) >> 3;
    int sw  = (lin & 7) * cpx + (lin >> 3);
    int bx = sw % gridDim.x, by = sw / gridDim.x;
    int m0 = by * BM, n0 = bx * 128;
    const bool lact = (NT == 6) && (n0 < NP1);

    int wm = (wave >> 1) * 64, wn = (wave & 1) * 64;
    f32x4 acc[4][4] = {};

    int l7 = lane & 7, l8 = lane >> 3;
    int lc = l7 ^ l8;                 // logical chunk at staging slot
    int lane15 = lane & 15, rsel = lane >> 4;
    int pH = (rsel ^ l7) * 8;
    int pM = ((4 | rsel) ^ l7) * 8;
    int aLrow = (lane15 >> 1) * 64 + (((((lane & 1) << 2) | rsel) ^ (lane15 >> 1)) * 8);
    int wslot = wave;

    auto stage = [&](int buf, int k0) {
        if constexpr (NT == 6) {
            #pragma unroll
            for (int j = 0; j < 4; ++j) {            // AHM: 32 groups
                int g = j * 8 + wslot;
                int r = g * 8 + l8;
                const u16* src = (lc >= 4 ? aM : aH) + (size_t)(m0 + r) * K + k0 + (lc & 3) * 8;
                gld_lds16u(src, &AHM[buf][g * 512 + lane * 8]);
            }
            #pragma unroll
            for (int j = 0; j < 2; ++j) {            // BHM: 16 groups
                int g = j * 8 + wslot;
                int r = g * 8 + l8;
                const u16* src = (lc >= 4 ? bM : bH) + (size_t)(n0 + r) * K + k0 + (lc & 3) * 8;
                gld_lds16u(src, &BHM[buf][g * 512 + lane * 8]);
            }
            if (lact) {
                #pragma unroll
                for (int j = 0; j < 2; ++j) {        // ALp: 16 groups (2 rows/LDS row)
                    int g = j * 8 + wslot;
                    int R = g * 8 + l8;
                    int rr = 2 * R + (lc >> 2);
                    const u16* src = aL + (size_t)(m0 + rr) * K + k0 + (lc & 3) * 8;
                    gld_lds16u(src, &ALp[buf][g * 512 + lane * 8]);
                }
                {                                     // BLp: 8 groups
                    int g = wslot;
                    int R = g * 8 + l8;
                    int rr = 2 * R + (lc >> 2);
                    const u16* src = bL + (size_t)(n0 + rr) * K + k0 + (lc & 3) * 8;
                    gld_lds16u(src, &BLp[buf][g * 512 + lane * 8]);
                }
            }
        } else {
            #pragma unroll
            for (int j = 0; j < 4; ++j) {            // AHM: 16 groups
                int g = j * 4 + wslot;
                int r = g * 8 + l8;
                const u16* src = (lc >= 4 ? aM : aH) + (size_t)(m0 + r) * K + k0 + (lc & 3) * 8;
                gld_lds16u(src, &AHM[buf][g * 512 + lane * 8]);
            }
            #pragma unroll
            for (int j = 0; j < 4; ++j) {            // BHM: 16 groups
                int g = j * 4 + wslot;
                int r = g * 8 + l8;
                const u16* src = (lc >= 4 ? bM : bH) + (size_t)(n0 + r) * K + k0 + (lc & 3) * 8;
                gld_lds16u(src, &BHM[buf][g * 512 + lane * 8]);
            }
        }
    };

    auto compute = [&](int buf) {
        frag8 ah[4], am[4], al[(NT == 6) ? 4 : 1];
        #pragma unroll
        for (int mi = 0; mi < 4; ++mi) {
            int rr = wm + mi * 16 + lane15;
            const u16* bp = &AHM[buf][rr * 64];
            ah[mi] = *(const frag8*)&bp[pH];
            am[mi] = *(const frag8*)&bp[pM];
            if constexpr (NT == 6)
                if (lact) al[mi] = *(const frag8*)&ALp[buf][(wm >> 1) * 64 + mi * 512 + aLrow];
        }
        #pragma unroll
        for (int ni = 0; ni < 4; ++ni) {
            int rb = wn + ni * 16 + lane15;
            const u16* bp = &BHM[buf][rb * 64];
            frag8 bh = *(const frag8*)&bp[pH];
            frag8 bm = *(const frag8*)&bp[pM];
            if constexpr (NT == 6) {
                if (lact) {
                    frag8 bl = *(const frag8*)&BLp[buf][(wn >> 1) * 64 + ni * 512 + aLrow];
                    #pragma unroll
                    for (int mi = 0; mi < 4; ++mi) {
                        acc[mi][ni] = __builtin_amdgcn_mfma_f32_16x16x32_bf16(ah[mi], bm, acc[mi][ni], 0, 0, 0);
                        acc[mi][ni] = __builtin_amdgcn_mfma_f32_16x16x32_bf16(am[mi], bh, acc[mi][ni], 0, 0, 0);
                        acc[mi][ni] = __builtin_amdgcn_mfma_f32_16x16x32_bf16(ah[mi], bl, acc[mi][ni], 0, 0, 0);
                        acc[mi][ni] = __builtin_amdgcn_mfma_f32_16x16x32_bf16(al[mi], bh, acc[mi][ni], 0, 0, 0);
                        acc[mi][ni] = __builtin_amdgcn_mfma_f32_16x16x32_bf16(am[mi], bm, acc[mi][ni], 0, 0, 0);
                        acc[mi][ni] = __builtin_amdgcn_mfma_f32_16x16x32_bf16(ah[mi], bh, acc[mi][ni], 0, 0, 0);
                    }
                } else {
                    #pragma unroll
                    for (int mi = 0; mi < 4; ++mi) {
                        acc[mi][ni] = __builtin_amdgcn_mfma_f32_16x16x32_bf16(ah[mi], bm, acc[mi][ni], 0, 0, 0);
                        acc[mi][ni] = __builtin_amdgcn_mfma_f32_16x16x32_bf16(am[mi], bh, acc[mi][ni], 0, 0, 0);
                        acc[mi][ni] = __builtin_amdgcn_mfma_f32_16x16x32_bf16(ah[mi], bh, acc[mi][ni], 0, 0, 0);
                    }
                }
            } else {
                #pragma unroll
                for (int mi = 0; mi < 4; ++mi) {
                    acc[mi][ni] = __builtin_amdgcn_mfma_f32_16x16x32_bf16(ah[mi], bm, acc[mi][ni], 0, 0, 0);
                    acc[mi][ni] = __builtin_amdgcn_mfma_f32_16x16x32_bf16(am[mi], bh, acc[mi][ni], 0, 0, 0);
                    acc[mi][ni] = __builtin_amdgcn_mfma_f32_16x16x32_bf16(ah[mi], bh, acc[mi][ni], 0, 0, 0);
                }
            }
        }
    };

    int ns = K >> 5;
    stage(0, 0);
    asm volatile("" ::: "memory");
    int cur = 0;
    for (int s = 0; s < ns - 1; ++s) {
        stage(cur ^ 1, (s + 1) * 32);
        if constexpr (NT == 6) {
            if (lact) asm volatile("s_waitcnt vmcnt(9)" ::: "memory");
            else      asm volatile("s_waitcnt vmcnt(6)" ::: "memory");
        } else {
            asm volatile("s_waitcnt vmcnt(8)" ::: "memory");
        }
        __builtin_amdgcn_sched_barrier(0);
        __builtin_amdgcn_s_barrier();
        compute(cur);
        __builtin_amdgcn_s_barrier();
        cur ^= 1;
    }
    asm volatile("s_waitcnt vmcnt(0)" ::: "memory");
    __builtin_amdgcn_sched_barrier(0);
    __builtin_amdgcn_s_barrier();
    compute(cur);

    const bool dosplit = (cH != nullptr);
    #pragma unroll
    for (int ni = 0; ni < 4; ++ni) {
        int ncol = n0 + wn + ni * 16 + (lane & 15);
        bool r1 = (ncol < N1);
        float* Cp; int ld, cc;
        if (r1) { Cp = C; ld = ldC; cc = ncol; }
        else if (C2 != nullptr && ncol >= NP1) { Cp = C2; ld = 768; cc = ncol - NP1; }
        else continue;
        float bs = r1 ? bias[ncol] : bias2[cc];
        #pragma unroll
        for (int mi = 0; mi < 4; ++mi) {
            #pragma unroll
            for (int r = 0; r < 4; ++r) {
                int mrow = m0 + wm + mi * 16 + (lane >> 4) * 4 + r;
                float val = acc[mi][ni][r] + bs;
                if (act == 1) val = 1.f / (1.f + expf(-val));
                if (resid && r1) val += resid[(size_t)mrow * ld + cc];
                Cp[(size_t)mrow * ld + cc] = val;
                if (dosplit && r1) {
                    unsigned H, M, L;
                    split3u(val, H, M, L);
                    cH[(size_t)mrow * ld + cc] = (u16)(H >> 16);
                    cM[(size_t)mrow * ld + cc] = (u16)(M >> 16);
                }
            }
        }
    }
}

// ---------------- causal conv + silu -> split planes -----------------------
__global__ void conv_split(const float* __restrict__ xt, const float* __restrict__ cw,
                           const float* __restrict__ cb, u16* __restrict__ xcH,
                           u16* __restrict__ xcM, u16* __restrict__ xcL)
{
    size_t idx = (size_t)blockIdx.x * blockDim.x + threadIdx.x;
    if (idx >= (size_t)NROW * UPD) return;
    int ch = idx % UPD;
    int s = (int)((idx / UPD) % SB);
    int b = (int)(idx / ((size_t)UPD * SB));
    float acc = cb[0];
    #pragma unroll
    for (int j = 0; j < KER; ++j) {
        int sj = s - (KER - 1) + j;
        if (sj >= 0) acc += cw[j] * xt[((size_t)b * SB + sj) * UPD + ch];
    }
    float v = acc / (1.f + expf(-acc));
    unsigned H, M, L;
    split3u(v, H, M, L);
    xcH[idx] = (u16)(H >> 16);
    xcM[idx] = (u16)(M >> 16);
    xcL[idx] = (u16)(L >> 16);
}

// ---------------- gates from proj (verbatim) -------------------------------
__global__ __launch_bounds__(64) void gates_kernel(
    const float* __restrict__ proj, float* __restrict__ lf,
    float* __restrict__ ic, float* __restrict__ wC)
{
    int cid = blockIdx.x;
    int l = threadIdx.x;
    int b = cid >> 9;
    int nh = (cid >> 6) & 7;
    int c = cid & 63;
    int s = c * CS + l;
    size_t row = ((size_t)b * SB + s) * FUSED;
    float ip = proj[row + nh];
    float fp = proj[row + NHD + nh];
    ip = 15.f * tanhf(ip * (1.f / 15.f));
    fp = 15.f * tanhf(fp * (1.f / 15.f));
    float mx = fmaxf(ip, fp);
    float ig = expf(ip - mx);
    float fg = expf(fp - mx);
    float v = logf(fg + 1e-8f);
    for (int off = 1; off < 64; off <<= 1) {
        float u = __shfl_up(v, off);
        if (l >= off) v += u;
    }
    float last = __shfl(v, 63);
    lf[cid * CS + l] = v;
    ic[cid * CS + l] = ig;
    wC[cid * CS + l] = expf(v - last) * ig;
}

// ---------------- per-chunk states CiT[e][d], n_c[d] -----------------------
// reads k,v directly from proj (k scaled inline, same fp32 mul as repack).
__global__ __launch_bounds__(256) void chunk_outer_kernel(
    const float* __restrict__ proj, const float* __restrict__ wC,
    float* __restrict__ Cc, float* __restrict__ nc)
{
    __shared__ float kL[CS * HDIM], vL[CS * HDIM], wL[CS];
    int cid = blockIdx.x, t = threadIdx.x;
    int b = cid >> 9, nh = (cid >> 6) & 7, c = cid & 63;
    const float* pg = proj + ((size_t)b * SB + (size_t)c * CS) * FUSED + 2 * NHD + nh * HDIM;
    for (int idx = t; idx < CS * HDIM; idx += 256) {
        int row = idx / HDIM, col = idx - row * HDIM;
        kL[idx] = pg[(size_t)row * FUSED + HID + col] * KSCALE;
        vL[idx] = pg[(size_t)row * FUSED + 2 * HID + col];
    }
    if (t < CS) wL[t] = wC[cid * CS + t];
    __syncthreads();
    int eb = t >> 3;
    int db = t & 7;
    float4 acc[3][3];
    #pragma unroll
    for (int e2 = 0; e2 < 3; ++e2)
        #pragma unroll
        for (int x = 0; x < 3; ++x) acc[e2][x] = make_float4(0.f, 0.f, 0.f, 0.f);
    for (int l = 0; l < CS; ++l) {
        float w = wL[l];
        float wk[3];
        #pragma unroll
        for (int e2 = 0; e2 < 3; ++e2) wk[e2] = w * kL[l * HDIM + 3 * eb + e2];
        const float* vr = &vL[l * HDIM + 12 * db];
        float4 vv[3];
        #pragma unroll
        for (int x = 0; x < 3; ++x) vv[x] = *(const float4*)(vr + 4 * x);
        #pragma unroll
        for (int e2 = 0; e2 < 3; ++e2)
            #pragma unroll
            for (int x = 0; x < 3; ++x) {
                acc[e2][x].x += wk[e2] * vv[x].x;
                acc[e2][x].y += wk[e2] * vv[x].y;
                acc[e2][x].z += wk[e2] * vv[x].z;
                acc[e2][x].w += wk[e2] * vv[x].w;
            }
    }
    float* Cb = Cc + (size_t)cid * HDIM * HDIM;
    #pragma unroll
    for (int e2 = 0; e2 < 3; ++e2)
        #pragma unroll
        for (int x = 0; x < 3; ++x)
            *(float4*)&Cb[(size_t)(3 * eb + e2) * HDIM + 12 * db + 4 * x] = acc[e2][x];
    if (t < HDIM) {
        float acc2 = 0.f;
        for (int l = 0; l < CS; ++l) acc2 += wL[l] * kL[l * HDIM + t];
        nc[(size_t)cid * HDIM + t] = acc2;
    }
}

// ---------------- exclusive chunk scan (verbatim) --------------------------
__global__ void scan_kernel(float* __restrict__ Cc, float* __restrict__ nc)
{
    int gid = blockIdx.x * blockDim.x + threadIdx.x;
    const int NCE = BB * NHD * HDIM * HDIM;
    if (gid < NCE) {
        int bh = gid / (HDIM * HDIM);
        int ent = gid % (HDIM * HDIM);
        float run = 0.f;
        float* base = Cc + (size_t)bh * NCH * HDIM * HDIM + ent;
        for (int c = 0; c < NCH; ++c) {
            float tv = base[(size_t)c * HDIM * HDIM];
            base[(size_t)c * HDIM * HDIM] = run;
            run += tv;
        }
    } else {
        int g2 = gid - NCE;
        if (g2 < BB * NHD * HDIM) {
            int bh = g2 / HDIM, ent = g2 % HDIM;
            float run = 0.f;
            float* base = nc + (size_t)bh * NCH * HDIM + ent;
            for (int c = 0; c < NCH; ++c) {
                float tv = base[c * HDIM];
                base[c * HDIM] = run;
                run += tv;
            }
        }
    }
}

// ---------------- intra-chunk attention ------------------------------------
// q/k/v read directly from proj (k scaled inline -> bit-identical to repack).
// Second half re-blocked 2 i-rows x 12 d-cols (round-5).
__global__ __launch_bounds__(256) void attn_kernel(
    const float* __restrict__ proj, const float* __restrict__ lf, const float* __restrict__ ic,
    const float* __restrict__ CiT, const float* __restrict__ ni,
    float* __restrict__ hout)
{
    __shared__ float qL[64 * 100];
    __shared__ float kL[64 * 100];
    __shared__ float lfL[64], icL[64], niL[96], dinvL[64];
    int cid = blockIdx.x, t = threadIdx.x;
    int b = cid >> 9, nh = (cid >> 6) & 7, c = cid & 63;
    const float* pq = proj + ((size_t)b * SB + (size_t)c * CS) * FUSED + 2 * NHD + nh * HDIM;
    const float* pk = pq + HID;
    const float* pv = pq + 2 * HID;
    #pragma unroll
    for (int it = 0; it < 6; ++it) {
        int idx = t + it * 256;
        int row = idx / 24, col = (idx % 24) * 4;
        *(float4*)&qL[row * 100 + col] = *(const float4*)(pq + (size_t)row * FUSED + col);
        float4 kv = *(const float4*)(pk + (size_t)row * FUSED + col);
        kv.x *= KSCALE; kv.y *= KSCALE; kv.z *= KSCALE; kv.w *= KSCALE;
        *(float4*)&kL[row * 100 + col] = kv;
    }
    if (t < 64) { lfL[t] = lf[cid * CS + t]; icL[t] = ic[cid * CS + t]; }
    else if (t < 160) { niL[t - 64] = ni[(size_t)cid * HDIM + (t - 64)]; }
    __syncthreads();

    int i = t >> 2, g = t & 3;
    const float* qrow = qL + i * 100;
    float sc[16];
    #pragma unroll
    for (int jj = 0; jj < 16; ++jj) sc[jj] = 0.f;
    for (int d4 = 0; d4 < 24; ++d4) {
        float4 qv = *(const float4*)(qrow + 4 * d4);
        #pragma unroll
        for (int jj = 0; jj < 16; ++jj) {
            float4 kv = *(const float4*)(kL + (g + 4 * jj) * 100 + 4 * d4);
            sc[jj] += qv.x * kv.x + qv.y * kv.y + qv.z * kv.z + qv.w * kv.w;
        }
    }
    float lfi = lfL[i];
    float wv[16];
    #pragma unroll
    for (int jj = 0; jj < 16; ++jj) {
        int j = g + 4 * jj;
        wv[jj] = (j < i) ? icL[j] * expf(lfi - lfL[j]) : 0.f;
    }
    float den = 0.f;
    #pragma unroll
    for (int jj = 0; jj < 16; ++jj) den += wv[jj] * sc[jj];
    #pragma unroll
    for (int dd = 0; dd < 24; ++dd) {
        int d = 24 * g + dd;
        den += niL[d] * qrow[d];
    }
    float m = -1e30f;
    #pragma unroll
    for (int jj = 0; jj < 16; ++jj) { int j = g + 4 * jj; if (j < i) m = fmaxf(m, sc[jj]); }
    m = fmaxf(m, __shfl_xor(m, 1)); m = fmaxf(m, __shfl_xor(m, 2));
    float p = 0.f;
    #pragma unroll
    for (int jj = 0; jj < 16; ++jj) {
        int j = g + 4 * jj;
        sc[jj] = (j < i) ? expf(sc[jj] - m) : 0.f;
        p += sc[jj];
    }
    p += __shfl_xor(p, 1); p += __shfl_xor(p, 2);
    float pinv = (p > 0.f) ? 1.f / p : 0.f;
    __syncthreads();
    float* awL = kL;
    #pragma unroll
    for (int jj = 0; jj < 16; ++jj) {
        int j = g + 4 * jj;
        awL[i * 68 + j] = sc[jj] * pinv * wv[jj];
    }
    den += __shfl_xor(den, 1); den += __shfl_xor(den, 2);
    if ((t & 3) == 0) dinvL[i] = 1.f / fmaxf(den, 1.f);
    __syncthreads();

    // ---- re-blocked AV + h_init: 2 i-rows x 12 d-cols per thread ----
    int i0 = (t >> 3) << 1, db = (t & 7) * 12;
    float4 h4[2][3];
    #pragma unroll
    for (int r = 0; r < 2; ++r)
        #pragma unroll
        for (int x = 0; x < 3; ++x) h4[r][x] = make_float4(0.f, 0.f, 0.f, 0.f);
    const float* vb = pv + db;
    const float* aw0 = awL + i0 * 68;
    for (int j = 0; j < 64; ++j) {
        float a0 = aw0[j];
        float a1 = aw0[68 + j];
        const float4* vr = (const float4*)(vb + (size_t)j * FUSED);
        #pragma unroll
        for (int x = 0; x < 3; ++x) {
            float4 vv = vr[x];
            h4[0][x].x += a0 * vv.x; h4[0][x].y += a0 * vv.y;
            h4[0][x].z += a0 * vv.z; h4[0][x].w += a0 * vv.w;
            h4[1][x].x += a1 * vv.x; h4[1][x].y += a1 * vv.y;
            h4[1][x].z += a1 * vv.z; h4[1][x].w += a1 * vv.w;
        }
    }
    const float* Cb = CiT + (size_t)cid * (HDIM * HDIM) + db;
    const float* qr0 = qL + i0 * 100;
    const float* qr1 = qr0 + 100;
    for (int e = 0; e < 96; ++e) {
        float q0 = qr0[e], q1 = qr1[e];
        const float4* cr = (const float4*)(Cb + e * HDIM);
        #pragma unroll
        for (int x = 0; x < 3; ++x) {
            float4 cv = cr[x];
            h4[0][x].x += q0 * cv.x; h4[0][x].y += q0 * cv.y;
            h4[0][x].z += q0 * cv.z; h4[0][x].w += q0 * cv.w;
            h4[1][x].x += q1 * cv.x; h4[1][x].y += q1 * cv.y;
            h4[1][x].z += q1 * cv.z; h4[1][x].w += q1 * cv.w;
        }
    }
    float di0 = dinvL[i0], di1 = dinvL[i0 + 1];
    int s0 = c * CS + i0;
    float4* hr0 = (float4*)(hout + (((size_t)b * SB + s0) * NHD + nh) * HDIM + db);
    float4* hr1 = (float4*)(hout + (((size_t)b * SB + s0 + 1) * NHD + nh) * HDIM + db);
    #pragma unroll
    for (int x = 0; x < 3; ++x) {
        float4 h0 = h4[0][x], h1 = h4[1][x];
        h0.x *= di0; h0.y *= di0; h0.z *= di0; h0.w *= di0;
        h1.x *= di1; h1.y *= di1; h1.z *= di1; h1.w *= di1;
        hr0[x] = h0;
        hr1[x] = h1;
    }
}

// ---------------- LN(o*h)+skip, *silu(rt) -> split planes ------------------
__global__ __launch_bounds__(256) void ln_hid_split(
    const float* __restrict__ h, const float* __restrict__ o,
    const float* __restrict__ xskip, const float* __restrict__ rt,
    const float* __restrict__ w, const float* __restrict__ bb,
    u16* __restrict__ oH, u16* __restrict__ oM)
{
    int row = blockIdx.x;
    size_t base = (size_t)row * HID;
    int c0 = threadIdx.x, c1 = threadIdx.x + 256, c2 = threadIdx.x + 512;
    float v0 = o[base + c0] * h[base + c0];
    float v1 = o[base + c1] * h[base + c1];
    float v2 = o[base + c2] * h[base + c2];
    float s = v0 + v1 + v2;
    float ss = v0*v0 + v1*v1 + v2*v2;
    for (int off = 32; off; off >>= 1) { s += __shfl_xor(s, off); ss += __shfl_xor(ss, off); }
    __shared__ float red[8];
    int wid = threadIdx.x >> 6;
    if ((threadIdx.x & 63) == 0) { red[wid] = s; red[4 + wid] = ss; }
    __syncthreads();
    s = red[0] + red[1] + red[2] + red[3];
    ss = red[4] + red[5] + red[6] + red[7];
    float mean = s * (1.f / HID);
    float var = ss * (1.f / HID) - mean * mean;
    float inv = rsqrtf(var + 1e-6f);
    float g0 = rt[base + c0], g1 = rt[base + c1], g2 = rt[base + c2];
    float r0 = ((v0 - mean) * inv * w[c0] + bb[c0] + xskip[base + c0]) * (g0 / (1.f + expf(-g0)));
    float r1 = ((v1 - mean) * inv * w[c1] + bb[c1] + xskip[base + c1]) * (g1 / (1.f + expf(-g1)));
    float r2 = ((v2 - mean) * inv * w[c2] + bb[c2] + xskip[base + c2]) * (g2 / (1.f + expf(-g2)));
    unsigned H, M, L;
    split3u(r0, H, M, L); oH[base+c0]=(u16)(H>>16); oM[base+c0]=(u16)(M>>16);
    split3u(r1, H, M, L); oH[base+c1]=(u16)(H>>16); oM[base+c1]=(u16)(M>>16);
    split3u(r2, H, M, L); oH[base+c2]=(u16)(H>>16); oM[base+c2]=(u16)(M>>16);
}

extern "C" void kernel_launch(void* const* d_in, const int* in_sizes, int n_in,
                              void* d_out, int out_size, void* d_ws, size_t ws_size,
                              hipStream_t stream)
{
    const float* x       = (const float*)d_in[0];
    const float* ln_in_w = (const float*)d_in[1];
    const float* ln_in_b = (const float*)d_in[2];
    const float* ln_hid_w= (const float*)d_in[3];
    const float* ln_hid_b= (const float*)d_in[4];
    const float* up_l_w  = (const float*)d_in[5];
    const float* up_l_b  = (const float*)d_in[6];
    const float* up_r_w  = (const float*)d_in[7];
    const float* up_r_b  = (const float*)d_in[8];
    const float* down_w  = (const float*)d_in[9];
    const float* down_b  = (const float*)d_in[10];
    const float* conv_w  = (const float*)d_in[11];
    const float* conv_b  = (const float*)d_in[12];
    const float* skip_w  = (const float*)d_in[13];
    const float* skip_b  = (const float*)d_in[14];
    const float* fused_w = (const float*)d_in[15];
    const float* fused_b = (const float*)d_in[16];
    const float* wo_w    = (const float*)d_in[17];
    const float* wo_b    = (const float*)d_in[18];
    float* out = (float*)d_out;

    float* ws = (float*)d_ws;
    // combined up planes: [2304 rows x 768]: rows 0..1535 up_l, 1536..2303 up_r
    u16* wupH = (u16*)(ws + O_WUP);    u16* wupM = wupH + 1769472; u16* wupL = wupM + 1769472;
    u16* wwoH  = (u16*)(ws + O_WWO);   u16* wwoM  = wwoH  + 1179648;
    u16* wdwnH = (u16*)(ws + O_WDOWN); u16* wdwnM = wdwnH + 589824;
    // combined fused planes: [3200 rows x 1536]: 0..2431 fused(+pad), 2432..3199 skip
    u16* wfusH = (u16*)(ws + O_WFUS);  u16* wfusM = wfusH + 4915200; u16* wfusL = wfusM + 4915200;
    float* rt    = ws + O_RT;
    float* xskip = ws + O_XSKIP;
    float* lf    = ws + O_LF;
    float* ic    = ws + O_IC;
    float* wC    = ws + O_WC;
    float* nc    = ws + O_NC;
    u16* xnH = (u16*)(ws + O_XN);  u16* xnM = xnH + 6291456; u16* xnL = xnM + 6291456;
    float* xt = ws + O_XT;
    u16* xtH = (u16*)(ws + O_XTS); u16* xtM = xtH + 12582912;
    u16* xcH = (u16*)(ws + O_XTS); u16* xcM = xcH + 12582912; u16* xcL = xcM + 12582912;
    float* proj = ws + O_PROJ;
    float* Cc = ws + O_CC;
    float* h  = ws + O_H;
    u16* out1H = (u16*)(ws + O_OUT1); u16* out1M = out1H + 6291456;
    float* o = (float*)d_out;

    // 0. weight transpose + 3-way bf16 split into merged layouts
    tpose_split<<<dim3(12, 24), 256, 0, stream>>>(up_l_w, wupH, wupM, wupL, 768, 1536);
    tpose_split<<<dim3(12, 12), 256, 0, stream>>>(up_r_w, wupH + 1179648, wupM + 1179648, nullptr, 768, 768);
    tpose_split<<<dim3(24, 38), 256, 0, stream>>>(fused_w, wfusH, wfusM, wfusL, 1536, 2320);
    tpose_split<<<dim3(24, 12), 256, 0, stream>>>(skip_w, wfusH + 3735552, wfusM + 3735552, nullptr, 1536, 768);
    tpose_split<<<dim3(24, 12), 256, 0, stream>>>(wo_w, wwoH, wwoM, nullptr, 1536, 768);
    tpose_split<<<dim3(12, 12), 256, 0, stream>>>(down_w, wdwnH, wdwnM, nullptr, 768, 768);
    // 1. input LN -> xn planes
    ln_in_split<<<NROW, 256, 0, stream>>>(x, ln_in_w, ln_in_b, xnH, xnM, xnL);
    // 2. merged up: region1 cols<1536 -> xt (6-term, +xtH/M), region2 -> rt (3-term)
    gemm_sp<6,512><<<dim3(18, 32), 512, 0, stream>>>(xnH, xnM, xnL, wupH, wupM, wupL,
        up_l_b, nullptr, xt, xtH, xtM, UPD, UPD, UPD, rt, up_r_b, D_IN, 0);
    // 3. wo BEFORE conv (conv output planes recycle the xtH/M region)
    gemm_sp<3,256><<<dim3(6, 64), 256, 0, stream>>>(xtH, xtM, nullptr, wwoH, wwoM, nullptr,
        wo_b, nullptr, o, nullptr, nullptr, HID, HID, 1 << 30, nullptr, nullptr, UPD, 1);
    // 4. causal conv + silu -> xc planes
    {
        size_t tot = (size_t)NROW * UPD;
        conv_split<<<(unsigned)((tot + 255) / 256), 256, 0, stream>>>(xt, conv_w, conv_b, xcH, xcM, xcL);
    }
    // 5. merged fused: region1 cols<2320 -> proj (6-term), region2 (>=2432) -> xskip (3-term)
    gemm_sp<6,512><<<dim3(25, 32), 512, 0, stream>>>(xcH, xcM, xcL, wfusH, wfusM, wfusL,
        fused_b, nullptr, proj, nullptr, nullptr, FUSED, FUSED, 2432, xskip, skip_b, UPD, 0);
    // 6. gates from proj
    gates_kernel<<<NCHUNK, 64, 0, stream>>>(proj, lf, ic, wC);
    // 7. per-chunk states (k,v direct from proj) + exclusive scan
    chunk_outer_kernel<<<NCHUNK, 256, 0, stream>>>(proj, wC, Cc, nc);
    {
        int tot = BB * NHD * HDIM * HDIM + BB * NHD * HDIM;
        scan_kernel<<<(tot + 255) / 256, 256, 0, stream>>>(Cc, nc);
    }
    // 8. intra-chunk attention (q,k,v direct from proj) -> h fp32
    attn_kernel<<<NCHUNK, 256, 0, stream>>>(proj, lf, ic, Cc, nc, h);
    // 9. LN(o*h) + skip, * silu(rt) -> out1 planes
    ln_hid_split<<<NROW, 256, 0, stream>>>(h, o, xskip, rt, ln_hid_w, ln_hid_b, out1H, out1M);
    // 10. down (3-term) + residual x -> out (overwrites o scratch)
    gemm_sp<3,256><<<dim3(6, 64), 256, 0, stream>>>(out1H, out1M, nullptr, wdwnH, wdwnM, nullptr,
        down_b, x, out, nullptr, nullptr, D_IN, D_IN, 1 << 30, nullptr, nullptr, HID, 0);
}

// Round 7
// 1118.653 us; speedup vs baseline: 1.0520x; 1.0520x over previous
//
#include <hip/hip_runtime.h>
#include <hip/hip_bf16.h>
#include <math.h>

#define D_IN  768
#define NHD   8
#define HDIM  96
#define HID   768
#define UPD   1536
#define FUSED 2320
#define KER   4
#define CS    64
#define NCH   64
#define SB    4096
#define BB    2
#define NROW  (BB*SB)          // 8192
#define NCHUNK (BB*NHD*NCH)    // 1024
#define KSCALE 0.10206207261596577f

using u16   = unsigned short;
using frag8 = __attribute__((ext_vector_type(8))) short;
using f32x4 = __attribute__((ext_vector_type(4))) float;

// ---- workspace offsets (floats). peak use 64,684,032 fl <= 65,404,928 cap ----
// R5 weight layout + R6 activation layout (repack-free).
#define O_WUPL   0            // 1,769,472
#define O_WUPR   1769472      //   589,824
#define O_WSKIP  2359296      // 1,179,648
#define O_WFUS   3538944      // 5,603,328
#define O_WWO    9142272      // 1,179,648
#define O_WDOWN  10321920     //   589,824
#define O_RT     10911744     // 6,291,456
#define O_XSKIP  17203200     // 6,291,456
#define O_LF     23494656
#define O_IC     23560192
#define O_WC     23625728
#define O_NC     23691264     // 98,304 -> ends 23,789,568
#define O_XN     23789568     // xn HML 9,437,184 (dead after up GEMMs)
#define O_XT     33226752     // xt fp32 12,582,912 (dead after conv)
#define O_XTS    45809664     // xtHM 12.58M -> xcHML 18.87M (ends 64,684,032)
#define O_PROJ   23789568     // proj 19,005,440 over dead xn+xt (live thru attn)
#define O_CC     45809664     // Cc 9,437,184 over dead xc planes
#define O_H      55246848     // h 6,291,456
#define O_OUT1   39518208     // out1 HM 6,291,456 (over proj tail, after attn)

__device__ __forceinline__ void gld_lds16u(const u16* g, u16* l) {
    __builtin_amdgcn_global_load_lds(
        (const __attribute__((address_space(1))) void*)g,
        (__attribute__((address_space(3))) void*)l, 16, 0, 0);
}

// split fp32 -> bf16 hi (RNE) + mid (trunc) + lo (trunc); residual ~2^-25
__device__ __forceinline__ void split3u(float f, unsigned &H, unsigned &M, unsigned &L) {
    unsigned u = __float_as_uint(f);
    unsigned hr = (u + 0x7fffu + ((u >> 16) & 1u)) & 0xffff0000u;
    H = hr;
    float rm = f - __uint_as_float(hr);
    unsigned mr = __float_as_uint(rm) & 0xffff0000u;
    M = mr;
    float rl = rm - __uint_as_float(mr);
    L = __float_as_uint(rl) & 0xffff0000u;
}

// ---------------- weight transpose + 3-way bf16 split ----------------------
__global__ __launch_bounds__(256) void tpose_split(
    const float* __restrict__ w, u16* __restrict__ tH, u16* __restrict__ tM,
    u16* __restrict__ tL, int K, int N)
{
    __shared__ float tile[64][65];
    int k0 = blockIdx.x * 64, n0 = blockIdx.y * 64;
    int t = threadIdx.x;
    int c = t & 63, r4 = t >> 6;
    #pragma unroll
    for (int it = 0; it < 16; ++it) {
        int r = r4 + it * 4;
        int n = n0 + c;
        tile[r][c] = (n < N) ? w[(size_t)(k0 + r) * N + n] : 0.f;
    }
    __syncthreads();
    #pragma unroll
    for (int it = 0; it < 16; ++it) {
        int nn = r4 + it * 4;
        float v = tile[c][nn];
        unsigned H, M, L;
        split3u(v, H, M, L);
        size_t idx = (size_t)(n0 + nn) * K + k0 + c;
        tH[idx] = (u16)(H >> 16);
        tM[idx] = (u16)(M >> 16);
        if (tL) tL[idx] = (u16)(L >> 16);
    }
}

// ---------------- LayerNorm over D_IN -> split planes ----------------------
__global__ __launch_bounds__(256) void ln_in_split(
    const float* __restrict__ x, const float* __restrict__ w,
    const float* __restrict__ b, u16* __restrict__ oH,
    u16* __restrict__ oM, u16* __restrict__ oL)
{
    int row = blockIdx.x;
    size_t base = (size_t)row * D_IN;
    int c0 = threadIdx.x, c1 = threadIdx.x + 256, c2 = threadIdx.x + 512;
    float v0 = x[base + c0], v1 = x[base + c1], v2 = x[base + c2];
    float s = v0 + v1 + v2;
    float ss = v0*v0 + v1*v1 + v2*v2;
    for (int off = 32; off; off >>= 1) { s += __shfl_xor(s, off); ss += __shfl_xor(ss, off); }
    __shared__ float red[8];
    int wid = threadIdx.x >> 6;
    if ((threadIdx.x & 63) == 0) { red[wid] = s; red[4 + wid] = ss; }
    __syncthreads();
    s = red[0] + red[1] + red[2] + red[3];
    ss = red[4] + red[5] + red[6] + red[7];
    float mean = s * (1.f / D_IN);
    float var = ss * (1.f / D_IN) - mean * mean;
    float inv = rsqrtf(var + 1e-6f);
    float r0 = (v0 - mean) * inv * w[c0] + b[c0];
    float r1 = (v1 - mean) * inv * w[c1] + b[c1];
    float r2 = (v2 - mean) * inv * w[c2] + b[c2];
    unsigned H, M, L;
    split3u(r0, H, M, L); oH[base+c0]=(u16)(H>>16); oM[base+c0]=(u16)(M>>16); oL[base+c0]=(u16)(L>>16);
    split3u(r1, H, M, L); oH[base+c1]=(u16)(H>>16); oM[base+c1]=(u16)(M>>16); oL[base+c1]=(u16)(L>>16);
    split3u(r2, H, M, L); oH[base+c2]=(u16)(H>>16); oM[base+c2]=(u16)(M>>16); oL[base+c2]=(u16)(L>>16);
}

// ---------------- MFMA GEMM, pre-split planes, 2-phase dbuf pipeline -------
// (round-5 version verbatim: monolithic compute, counted vmcnt,
//  2 barriers/K-step — best measured: fused 377-392 us.)
template<int NT, int NTH>
__global__ __launch_bounds__(NTH) void gemm_sp(
    const u16* __restrict__ aH, const u16* __restrict__ aM, const u16* __restrict__ aL,
    const u16* __restrict__ bH, const u16* __restrict__ bM, const u16* __restrict__ bL,
    const float* __restrict__ bias, const float* __restrict__ resid,
    float* __restrict__ C, u16* __restrict__ cH, u16* __restrict__ cM,
    int N, int K, int act)
{
    constexpr int BM = (NT == 6) ? 256 : 128;
    __shared__ u16 AHM[2][BM * 64];
    __shared__ u16 BHM[2][128 * 64];
    __shared__ u16 ALp[(NT == 6) ? 2 : 1][(NT == 6) ? 128 * 64 : 8];
    __shared__ u16 BLp[(NT == 6) ? 2 : 1][(NT == 6) ? 64 * 64 : 8];

    int t = threadIdx.x;
    int wave = t >> 6, lane = t & 63;
    // XCD-aware bijective swizzle (all grids are multiples of 8)
    int lin = blockIdx.y * gridDim.x + blockIdx.x;
    int cpx = (gridDim.x * gridDim.y) >> 3;
    int sw  = (lin & 7) * cpx + (lin >> 3);
    int bx = sw % gridDim.x, by = sw / gridDim.x;
    int m0 = by * BM, n0 = bx * 128;

    int wm = (wave >> 1) * 64, wn = (wave & 1) * 64;
    f32x4 acc[4][4] = {};

    int l7 = lane & 7, l8 = lane >> 3;
    int lc = l7 ^ l8;                 // logical chunk at staging slot
    int lane15 = lane & 15, rsel = lane >> 4;
    int pH = (rsel ^ l7) * 8;
    int pM = ((4 | rsel) ^ l7) * 8;
    int aLrow = (lane15 >> 1) * 64 + (((((lane & 1) << 2) | rsel) ^ (lane15 >> 1)) * 8);
    int wslot = wave;

    auto stage = [&](int buf, int k0) {
        if constexpr (NT == 6) {
            #pragma unroll
            for (int j = 0; j < 4; ++j) {            // AHM: 32 groups
                int g = j * 8 + wslot;
                int r = g * 8 + l8;
                const u16* src = (lc >= 4 ? aM : aH) + (size_t)(m0 + r) * K + k0 + (lc & 3) * 8;
                gld_lds16u(src, &AHM[buf][g * 512 + lane * 8]);
            }
            #pragma unroll
            for (int j = 0; j < 2; ++j) {            // BHM: 16 groups
                int g = j * 8 + wslot;
                int r = g * 8 + l8;
                const u16* src = (lc >= 4 ? bM : bH) + (size_t)(n0 + r) * K + k0 + (lc & 3) * 8;
                gld_lds16u(src, &BHM[buf][g * 512 + lane * 8]);
            }
            #pragma unroll
            for (int j = 0; j < 2; ++j) {            // ALp: 16 groups (2 rows/LDS row)
                int g = j * 8 + wslot;
                int R = g * 8 + l8;
                int rr = 2 * R + (lc >> 2);
                const u16* src = aL + (size_t)(m0 + rr) * K + k0 + (lc & 3) * 8;
                gld_lds16u(src, &ALp[buf][g * 512 + lane * 8]);
            }
            {                                         // BLp: 8 groups
                int g = wslot;
                int R = g * 8 + l8;
                int rr = 2 * R + (lc >> 2);
                const u16* src = bL + (size_t)(n0 + rr) * K + k0 + (lc & 3) * 8;
                gld_lds16u(src, &BLp[buf][g * 512 + lane * 8]);
            }
        } else {
            #pragma unroll
            for (int j = 0; j < 4; ++j) {            // AHM: 16 groups
                int g = j * 4 + wslot;
                int r = g * 8 + l8;
                const u16* src = (lc >= 4 ? aM : aH) + (size_t)(m0 + r) * K + k0 + (lc & 3) * 8;
                gld_lds16u(src, &AHM[buf][g * 512 + lane * 8]);
            }
            #pragma unroll
            for (int j = 0; j < 4; ++j) {            // BHM: 16 groups
                int g = j * 4 + wslot;
                int r = g * 8 + l8;
                const u16* src = (lc >= 4 ? bM : bH) + (size_t)(n0 + r) * K + k0 + (lc & 3) * 8;
                gld_lds16u(src, &BHM[buf][g * 512 + lane * 8]);
            }
        }
    };

    auto compute = [&](int buf) {
        frag8 ah[4], am[4], al[(NT == 6) ? 4 : 1];
        #pragma unroll
        for (int mi = 0; mi < 4; ++mi) {
            int rr = wm + mi * 16 + lane15;
            const u16* bp = &AHM[buf][rr * 64];
            ah[mi] = *(const frag8*)&bp[pH];
            am[mi] = *(const frag8*)&bp[pM];
            if constexpr (NT == 6)
                al[mi] = *(const frag8*)&ALp[buf][(wm >> 1) * 64 + mi * 512 + aLrow];
        }
        #pragma unroll
        for (int ni = 0; ni < 4; ++ni) {
            int rb = wn + ni * 16 + lane15;
            const u16* bp = &BHM[buf][rb * 64];
            frag8 bh = *(const frag8*)&bp[pH];
            frag8 bm = *(const frag8*)&bp[pM];
            if constexpr (NT == 6) {
                frag8 bl = *(const frag8*)&BLp[buf][(wn >> 1) * 64 + ni * 512 + aLrow];
                #pragma unroll
                for (int mi = 0; mi < 4; ++mi) {
                    acc[mi][ni] = __builtin_amdgcn_mfma_f32_16x16x32_bf16(ah[mi], bm, acc[mi][ni], 0, 0, 0);
                    acc[mi][ni] = __builtin_amdgcn_mfma_f32_16x16x32_bf16(am[mi], bh, acc[mi][ni], 0, 0, 0);
                    acc[mi][ni] = __builtin_amdgcn_mfma_f32_16x16x32_bf16(ah[mi], bl, acc[mi][ni], 0, 0, 0);
                    acc[mi][ni] = __builtin_amdgcn_mfma_f32_16x16x32_bf16(al[mi], bh, acc[mi][ni], 0, 0, 0);
                    acc[mi][ni] = __builtin_amdgcn_mfma_f32_16x16x32_bf16(am[mi], bm, acc[mi][ni], 0, 0, 0);
                    acc[mi][ni] = __builtin_amdgcn_mfma_f32_16x16x32_bf16(ah[mi], bh, acc[mi][ni], 0, 0, 0);
                }
            } else {
                #pragma unroll
                for (int mi = 0; mi < 4; ++mi) {
                    acc[mi][ni] = __builtin_amdgcn_mfma_f32_16x16x32_bf16(ah[mi], bm, acc[mi][ni], 0, 0, 0);
                    acc[mi][ni] = __builtin_amdgcn_mfma_f32_16x16x32_bf16(am[mi], bh, acc[mi][ni], 0, 0, 0);
                    acc[mi][ni] = __builtin_amdgcn_mfma_f32_16x16x32_bf16(ah[mi], bh, acc[mi][ni], 0, 0, 0);
                }
            }
        }
    };

    int ns = K >> 5;
    stage(0, 0);
    asm volatile("" ::: "memory");
    int cur = 0;
    for (int s = 0; s < ns - 1; ++s) {
        stage(cur ^ 1, (s + 1) * 32);
        if constexpr (NT == 6) asm volatile("s_waitcnt vmcnt(9)" ::: "memory");
        else                   asm volatile("s_waitcnt vmcnt(8)" ::: "memory");
        __builtin_amdgcn_sched_barrier(0);
        __builtin_amdgcn_s_barrier();
        compute(cur);
        __builtin_amdgcn_s_barrier();
        cur ^= 1;
    }
    asm volatile("s_waitcnt vmcnt(0)" ::: "memory");
    __builtin_amdgcn_sched_barrier(0);
    __builtin_amdgcn_s_barrier();
    compute(cur);

    const bool dosplit = (cH != nullptr);
    #pragma unroll
    for (int ni = 0; ni < 4; ++ni) {
        int ncol = n0 + wn + ni * 16 + (lane & 15);
        if (ncol >= N) continue;
        float bs = bias[ncol];
        #pragma unroll
        for (int mi = 0; mi < 4; ++mi) {
            #pragma unroll
            for (int r = 0; r < 4; ++r) {
                int mrow = m0 + wm + mi * 16 + (lane >> 4) * 4 + r;
                float val = acc[mi][ni][r] + bs;
                if (act == 1) val = 1.f / (1.f + expf(-val));
                if (resid) val += resid[(size_t)mrow * N + ncol];
                C[(size_t)mrow * N + ncol] = val;
                if (dosplit) {
                    unsigned H, M, L;
                    split3u(val, H, M, L);
                    cH[(size_t)mrow * N + ncol] = (u16)(H >> 16);
                    cM[(size_t)mrow * N + ncol] = (u16)(M >> 16);
                }
            }
        }
    }
}

// ---------------- causal conv + silu -> split planes -----------------------
__global__ void conv_split(const float* __restrict__ xt, const float* __restrict__ cw,
                           const float* __restrict__ cb, u16* __restrict__ xcH,
                           u16* __restrict__ xcM, u16* __restrict__ xcL)
{
    size_t idx = (size_t)blockIdx.x * blockDim.x + threadIdx.x;
    if (idx >= (size_t)NROW * UPD) return;
    int ch = idx % UPD;
    int s = (int)((idx / UPD) % SB);
    int b = (int)(idx / ((size_t)UPD * SB));
    float acc = cb[0];
    #pragma unroll
    for (int j = 0; j < KER; ++j) {
        int sj = s - (KER - 1) + j;
        if (sj >= 0) acc += cw[j] * xt[((size_t)b * SB + sj) * UPD + ch];
    }
    float v = acc / (1.f + expf(-acc));
    unsigned H, M, L;
    split3u(v, H, M, L);
    xcH[idx] = (u16)(H >> 16);
    xcM[idx] = (u16)(M >> 16);
    xcL[idx] = (u16)(L >> 16);
}

// ---------------- gates from proj (verbatim) -------------------------------
__global__ __launch_bounds__(64) void gates_kernel(
    const float* __restrict__ proj, float* __restrict__ lf,
    float* __restrict__ ic, float* __restrict__ wC)
{
    int cid = blockIdx.x;
    int l = threadIdx.x;
    int b = cid >> 9;
    int nh = (cid >> 6) & 7;
    int c = cid & 63;
    int s = c * CS + l;
    size_t row = ((size_t)b * SB + s) * FUSED;
    float ip = proj[row + nh];
    float fp = proj[row + NHD + nh];
    ip = 15.f * tanhf(ip * (1.f / 15.f));
    fp = 15.f * tanhf(fp * (1.f / 15.f));
    float mx = fmaxf(ip, fp);
    float ig = expf(ip - mx);
    float fg = expf(fp - mx);
    float v = logf(fg + 1e-8f);
    for (int off = 1; off < 64; off <<= 1) {
        float u = __shfl_up(v, off);
        if (l >= off) v += u;
    }
    float last = __shfl(v, 63);
    lf[cid * CS + l] = v;
    ic[cid * CS + l] = ig;
    wC[cid * CS + l] = expf(v - last) * ig;
}

// ---------------- per-chunk states CiT[e][d], n_c[d] (proj-direct, R6) -----
__global__ __launch_bounds__(256) void chunk_outer_kernel(
    const float* __restrict__ proj, const float* __restrict__ wC,
    float* __restrict__ Cc, float* __restrict__ nc)
{
    __shared__ float kL[CS * HDIM], vL[CS * HDIM], wL[CS];
    int cid = blockIdx.x, t = threadIdx.x;
    int b = cid >> 9, nh = (cid >> 6) & 7, c = cid & 63;
    const float* pg = proj + ((size_t)b * SB + (size_t)c * CS) * FUSED + 2 * NHD + nh * HDIM;
    for (int idx = t; idx < CS * HDIM; idx += 256) {
        int row = idx / HDIM, col = idx - row * HDIM;
        kL[idx] = pg[(size_t)row * FUSED + HID + col] * KSCALE;
        vL[idx] = pg[(size_t)row * FUSED + 2 * HID + col];
    }
    if (t < CS) wL[t] = wC[cid * CS + t];
    __syncthreads();
    int eb = t >> 3;
    int db = t & 7;
    float4 acc[3][3];
    #pragma unroll
    for (int e2 = 0; e2 < 3; ++e2)
        #pragma unroll
        for (int x = 0; x < 3; ++x) acc[e2][x] = make_float4(0.f, 0.f, 0.f, 0.f);
    for (int l = 0; l < CS; ++l) {
        float w = wL[l];
        float wk[3];
        #pragma unroll
        for (int e2 = 0; e2 < 3; ++e2) wk[e2] = w * kL[l * HDIM + 3 * eb + e2];
        const float* vr = &vL[l * HDIM + 12 * db];
        float4 vv[3];
        #pragma unroll
        for (int x = 0; x < 3; ++x) vv[x] = *(const float4*)(vr + 4 * x);
        #pragma unroll
        for (int e2 = 0; e2 < 3; ++e2)
            #pragma unroll
            for (int x = 0; x < 3; ++x) {
                acc[e2][x].x += wk[e2] * vv[x].x;
                acc[e2][x].y += wk[e2] * vv[x].y;
                acc[e2][x].z += wk[e2] * vv[x].z;
                acc[e2][x].w += wk[e2] * vv[x].w;
            }
    }
    float* Cb = Cc + (size_t)cid * HDIM * HDIM;
    #pragma unroll
    for (int e2 = 0; e2 < 3; ++e2)
        #pragma unroll
        for (int x = 0; x < 3; ++x)
            *(float4*)&Cb[(size_t)(3 * eb + e2) * HDIM + 12 * db + 4 * x] = acc[e2][x];
    if (t < HDIM) {
        float acc2 = 0.f;
        for (int l = 0; l < CS; ++l) acc2 += wL[l] * kL[l * HDIM + t];
        nc[(size_t)cid * HDIM + t] = acc2;
    }
}

// ---------------- exclusive chunk scan (verbatim) --------------------------
__global__ void scan_kernel(float* __restrict__ Cc, float* __restrict__ nc)
{
    int gid = blockIdx.x * blockDim.x + threadIdx.x;
    const int NCE = BB * NHD * HDIM * HDIM;
    if (gid < NCE) {
        int bh = gid / (HDIM * HDIM);
        int ent = gid % (HDIM * HDIM);
        float run = 0.f;
        float* base = Cc + (size_t)bh * NCH * HDIM * HDIM + ent;
        for (int c = 0; c < NCH; ++c) {
            float tv = base[(size_t)c * HDIM * HDIM];
            base[(size_t)c * HDIM * HDIM] = run;
            run += tv;
        }
    } else {
        int g2 = gid - NCE;
        if (g2 < BB * NHD * HDIM) {
            int bh = g2 / HDIM, ent = g2 % HDIM;
            float run = 0.f;
            float* base = nc + (size_t)bh * NCH * HDIM + ent;
            for (int c = 0; c < NCH; ++c) {
                float tv = base[c * HDIM];
                base[c * HDIM] = run;
                run += tv;
            }
        }
    }
}

// ---------------- intra-chunk attention (proj-direct, R6) ------------------
__global__ __launch_bounds__(256) void attn_kernel(
    const float* __restrict__ proj, const float* __restrict__ lf, const float* __restrict__ ic,
    const float* __restrict__ CiT, const float* __restrict__ ni,
    float* __restrict__ hout)
{
    __shared__ float qL[64 * 100];
    __shared__ float kL[64 * 100];
    __shared__ float lfL[64], icL[64], niL[96], dinvL[64];
    int cid = blockIdx.x, t = threadIdx.x;
    int b = cid >> 9, nh = (cid >> 6) & 7, c = cid & 63;
    const float* pq = proj + ((size_t)b * SB + (size_t)c * CS) * FUSED + 2 * NHD + nh * HDIM;
    const float* pk = pq + HID;
    const float* pv = pq + 2 * HID;
    #pragma unroll
    for (int it = 0; it < 6; ++it) {
        int idx = t + it * 256;
        int row = idx / 24, col = (idx % 24) * 4;
        *(float4*)&qL[row * 100 + col] = *(const float4*)(pq + (size_t)row * FUSED + col);
        float4 kv = *(const float4*)(pk + (size_t)row * FUSED + col);
        kv.x *= KSCALE; kv.y *= KSCALE; kv.z *= KSCALE; kv.w *= KSCALE;
        *(float4*)&kL[row * 100 + col] = kv;
    }
    if (t < 64) { lfL[t] = lf[cid * CS + t]; icL[t] = ic[cid * CS + t]; }
    else if (t < 160) { niL[t - 64] = ni[(size_t)cid * HDIM + (t - 64)]; }
    __syncthreads();

    int i = t >> 2, g = t & 3;
    const float* qrow = qL + i * 100;
    float sc[16];
    #pragma unroll
    for (int jj = 0; jj < 16; ++jj) sc[jj] = 0.f;
    for (int d4 = 0; d4 < 24; ++d4) {
        float4 qv = *(const float4*)(qrow + 4 * d4);
        #pragma unroll
        for (int jj = 0; jj < 16; ++jj) {
            float4 kv = *(const float4*)(kL + (g + 4 * jj) * 100 + 4 * d4);
            sc[jj] += qv.x * kv.x + qv.y * kv.y + qv.z * kv.z + qv.w * kv.w;
        }
    }
    float lfi = lfL[i];
    float wv[16];
    #pragma unroll
    for (int jj = 0; jj < 16; ++jj) {
        int j = g + 4 * jj;
        wv[jj] = (j < i) ? icL[j] * expf(lfi - lfL[j]) : 0.f;
    }
    float den = 0.f;
    #pragma unroll
    for (int jj = 0; jj < 16; ++jj) den += wv[jj] * sc[jj];
    #pragma unroll
    for (int dd = 0; dd < 24; ++dd) {
        int d = 24 * g + dd;
        den += niL[d] * qrow[d];
    }
    float m = -1e30f;
    #pragma unroll
    for (int jj = 0; jj < 16; ++jj) { int j = g + 4 * jj; if (j < i) m = fmaxf(m, sc[jj]); }
    m = fmaxf(m, __shfl_xor(m, 1)); m = fmaxf(m, __shfl_xor(m, 2));
    float p = 0.f;
    #pragma unroll
    for (int jj = 0; jj < 16; ++jj) {
        int j = g + 4 * jj;
        sc[jj] = (j < i) ? expf(sc[jj] - m) : 0.f;
        p += sc[jj];
    }
    p += __shfl_xor(p, 1); p += __shfl_xor(p, 2);
    float pinv = (p > 0.f) ? 1.f / p : 0.f;
    __syncthreads();
    float* awL = kL;
    #pragma unroll
    for (int jj = 0; jj < 16; ++jj) {
        int j = g + 4 * jj;
        awL[i * 68 + j] = sc[jj] * pinv * wv[jj];
    }
    den += __shfl_xor(den, 1); den += __shfl_xor(den, 2);
    if ((t & 3) == 0) dinvL[i] = 1.f / fmaxf(den, 1.f);
    __syncthreads();

    // ---- re-blocked AV + h_init: 2 i-rows x 12 d-cols per thread ----
    int i0 = (t >> 3) << 1, db = (t & 7) * 12;
    float4 h4[2][3];
    #pragma unroll
    for (int r = 0; r < 2; ++r)
        #pragma unroll
        for (int x = 0; x < 3; ++x) h4[r][x] = make_float4(0.f, 0.f, 0.f, 0.f);
    const float* vb = pv + db;
    const float* aw0 = awL + i0 * 68;
    for (int j = 0; j < 64; ++j) {
        float a0 = aw0[j];
        float a1 = aw0[68 + j];
        const float4* vr = (const float4*)(vb + (size_t)j * FUSED);
        #pragma unroll
        for (int x = 0; x < 3; ++x) {
            float4 vv = vr[x];
            h4[0][x].x += a0 * vv.x; h4[0][x].y += a0 * vv.y;
            h4[0][x].z += a0 * vv.z; h4[0][x].w += a0 * vv.w;
            h4[1][x].x += a1 * vv.x; h4[1][x].y += a1 * vv.y;
            h4[1][x].z += a1 * vv.z; h4[1][x].w += a1 * vv.w;
        }
    }
    const float* Cb = CiT + (size_t)cid * (HDIM * HDIM) + db;
    const float* qr0 = qL + i0 * 100;
    const float* qr1 = qr0 + 100;
    for (int e = 0; e < 96; ++e) {
        float q0 = qr0[e], q1 = qr1[e];
        const float4* cr = (const float4*)(Cb + e * HDIM);
        #pragma unroll
        for (int x = 0; x < 3; ++x) {
            float4 cv = cr[x];
            h4[0][x].x += q0 * cv.x; h4[0][x].y += q0 * cv.y;
            h4[0][x].z += q0 * cv.z; h4[0][x].w += q0 * cv.w;
            h4[1][x].x += q1 * cv.x; h4[1][x].y += q1 * cv.y;
            h4[1][x].z += q1 * cv.z; h4[1][x].w += q1 * cv.w;
        }
    }
    float di0 = dinvL[i0], di1 = dinvL[i0 + 1];
    int s0 = c * CS + i0;
    float4* hr0 = (float4*)(hout + (((size_t)b * SB + s0) * NHD + nh) * HDIM + db);
    float4* hr1 = (float4*)(hout + (((size_t)b * SB + s0 + 1) * NHD + nh) * HDIM + db);
    #pragma unroll
    for (int x = 0; x < 3; ++x) {
        float4 h0 = h4[0][x], h1 = h4[1][x];
        h0.x *= di0; h0.y *= di0; h0.z *= di0; h0.w *= di0;
        h1.x *= di1; h1.y *= di1; h1.z *= di1; h1.w *= di1;
        hr0[x] = h0;
        hr1[x] = h1;
    }
}

// ---------------- LN(o*h)+skip, *silu(rt) -> split planes ------------------
__global__ __launch_bounds__(256) void ln_hid_split(
    const float* __restrict__ h, const float* __restrict__ o,
    const float* __restrict__ xskip, const float* __restrict__ rt,
    const float* __restrict__ w, const float* __restrict__ bb,
    u16* __restrict__ oH, u16* __restrict__ oM)
{
    int row = blockIdx.x;
    size_t base = (size_t)row * HID;
    int c0 = threadIdx.x, c1 = threadIdx.x + 256, c2 = threadIdx.x + 512;
    float v0 = o[base + c0] * h[base + c0];
    float v1 = o[base + c1] * h[base + c1];
    float v2 = o[base + c2] * h[base + c2];
    float s = v0 + v1 + v2;
    float ss = v0*v0 + v1*v1 + v2*v2;
    for (int off = 32; off; off >>= 1) { s += __shfl_xor(s, off); ss += __shfl_xor(ss, off); }
    __shared__ float red[8];
    int wid = threadIdx.x >> 6;
    if ((threadIdx.x & 63) == 0) { red[wid] = s; red[4 + wid] = ss; }
    __syncthreads();
    s = red[0] + red[1] + red[2] + red[3];
    ss = red[4] + red[5] + red[6] + red[7];
    float mean = s * (1.f / HID);
    float var = ss * (1.f / HID) - mean * mean;
    float inv = rsqrtf(var + 1e-6f);
    float g0 = rt[base + c0], g1 = rt[base + c1], g2 = rt[base + c2];
    float r0 = ((v0 - mean) * inv * w[c0] + bb[c0] + xskip[base + c0]) * (g0 / (1.f + expf(-g0)));
    float r1 = ((v1 - mean) * inv * w[c1] + bb[c1] + xskip[base + c1]) * (g1 / (1.f + expf(-g1)));
    float r2 = ((v2 - mean) * inv * w[c2] + bb[c2] + xskip[base + c2]) * (g2 / (1.f + expf(-g2)));
    unsigned H, M, L;
    split3u(r0, H, M, L); oH[base+c0]=(u16)(H>>16); oM[base+c0]=(u16)(M>>16);
    split3u(r1, H, M, L); oH[base+c1]=(u16)(H>>16); oM[base+c1]=(u16)(M>>16);
    split3u(r2, H, M, L); oH[base+c2]=(u16)(H>>16); oM[base+c2]=(u16)(M>>16);
}

extern "C" void kernel_launch(void* const* d_in, const int* in_sizes, int n_in,
                              void* d_out, int out_size, void* d_ws, size_t ws_size,
                              hipStream_t stream)
{
    const float* x       = (const float*)d_in[0];
    const float* ln_in_w = (const float*)d_in[1];
    const float* ln_in_b = (const float*)d_in[2];
    const float* ln_hid_w= (const float*)d_in[3];
    const float* ln_hid_b= (const float*)d_in[4];
    const float* up_l_w  = (const float*)d_in[5];
    const float* up_l_b  = (const float*)d_in[6];
    const float* up_r_w  = (const float*)d_in[7];
    const float* up_r_b  = (const float*)d_in[8];
    const float* down_w  = (const float*)d_in[9];
    const float* down_b  = (const float*)d_in[10];
    const float* conv_w  = (const float*)d_in[11];
    const float* conv_b  = (const float*)d_in[12];
    const float* skip_w  = (const float*)d_in[13];
    const float* skip_b  = (const float*)d_in[14];
    const float* fused_w = (const float*)d_in[15];
    const float* fused_b = (const float*)d_in[16];
    const float* wo_w    = (const float*)d_in[17];
    const float* wo_b    = (const float*)d_in[18];
    float* out = (float*)d_out;

    float* ws = (float*)d_ws;
    u16* wuplH = (u16*)(ws + O_WUPL);  u16* wuplM = wuplH + 1179648; u16* wuplL = wuplM + 1179648;
    u16* wuprH = (u16*)(ws + O_WUPR);  u16* wuprM = wuprH + 589824;
    u16* wskpH = (u16*)(ws + O_WSKIP); u16* wskpM = wskpH + 1179648;
    u16* wfusH = (u16*)(ws + O_WFUS);  u16* wfusM = wfusH + 3735552; u16* wfusL = wfusM + 3735552;
    u16* wwoH  = (u16*)(ws + O_WWO);   u16* wwoM  = wwoH  + 1179648;
    u16* wdwnH = (u16*)(ws + O_WDOWN); u16* wdwnM = wdwnH + 589824;
    float* rt    = ws + O_RT;
    float* xskip = ws + O_XSKIP;
    float* lf    = ws + O_LF;
    float* ic    = ws + O_IC;
    float* wC    = ws + O_WC;
    float* nc    = ws + O_NC;
    u16* xnH = (u16*)(ws + O_XN);  u16* xnM = xnH + 6291456; u16* xnL = xnM + 6291456;
    float* xt = ws + O_XT;
    u16* xtH = (u16*)(ws + O_XTS); u16* xtM = xtH + 12582912;
    u16* xcH = (u16*)(ws + O_XTS); u16* xcM = xcH + 12582912; u16* xcL = xcM + 12582912;
    float* proj = ws + O_PROJ;
    float* Cc = ws + O_CC;
    float* h  = ws + O_H;
    u16* out1H = (u16*)(ws + O_OUT1); u16* out1M = out1H + 6291456;
    float* o = (float*)d_out;

    // 0. weight transpose + 3-way bf16 split (pad fused to 2432 rows)
    tpose_split<<<dim3(12, 24), 256, 0, stream>>>(up_l_w, wuplH, wuplM, wuplL, 768, 1536);
    tpose_split<<<dim3(12, 12), 256, 0, stream>>>(up_r_w, wuprH, wuprM, nullptr, 768, 768);
    tpose_split<<<dim3(24, 12), 256, 0, stream>>>(skip_w, wskpH, wskpM, nullptr, 1536, 768);
    tpose_split<<<dim3(24, 38), 256, 0, stream>>>(fused_w, wfusH, wfusM, wfusL, 1536, 2320);
    tpose_split<<<dim3(24, 12), 256, 0, stream>>>(wo_w, wwoH, wwoM, nullptr, 1536, 768);
    tpose_split<<<dim3(12, 12), 256, 0, stream>>>(down_w, wdwnH, wdwnM, nullptr, 768, 768);
    // 1. input LN -> xn planes
    ln_in_split<<<NROW, 256, 0, stream>>>(x, ln_in_w, ln_in_b, xnH, xnM, xnL);
    // 2. up projections: xt (6-term, + xtH/M planes for wo), rt (3-term)
    gemm_sp<6,512><<<dim3(12, 32), 512, 0, stream>>>(xnH, xnM, xnL, wuplH, wuplM, wuplL,
        up_l_b, nullptr, xt, xtH, xtM, UPD, D_IN, 0);
    gemm_sp<3,256><<<dim3(6, 64), 256, 0, stream>>>(xnH, xnM, nullptr, wuprH, wuprM, nullptr,
        up_r_b, nullptr, rt, nullptr, nullptr, HID, D_IN, 0);
    // 3. wo BEFORE conv (conv output planes recycle the xtH/M region)
    gemm_sp<3,256><<<dim3(6, 64), 256, 0, stream>>>(xtH, xtM, nullptr, wwoH, wwoM, nullptr,
        wo_b, nullptr, o, nullptr, nullptr, HID, UPD, 1);
    // 4. causal conv + silu -> xc planes
    {
        size_t tot = (size_t)NROW * UPD;
        conv_split<<<(unsigned)((tot + 255) / 256), 256, 0, stream>>>(xt, conv_w, conv_b, xcH, xcM, xcL);
    }
    // 5. skip (3-term); fused (6-term) -> proj
    gemm_sp<3,256><<<dim3(6, 64), 256, 0, stream>>>(xcH, xcM, nullptr, wskpH, wskpM, nullptr,
        skip_b, nullptr, xskip, nullptr, nullptr, HID, UPD, 0);
    gemm_sp<6,512><<<dim3(19, 32), 512, 0, stream>>>(xcH, xcM, xcL, wfusH, wfusM, wfusL,
        fused_b, nullptr, proj, nullptr, nullptr, FUSED, UPD, 0);
    // 6. gates from proj
    gates_kernel<<<NCHUNK, 64, 0, stream>>>(proj, lf, ic, wC);
    // 7. per-chunk states (k,v direct from proj) + exclusive scan
    chunk_outer_kernel<<<NCHUNK, 256, 0, stream>>>(proj, wC, Cc, nc);
    {
        int tot = BB * NHD * HDIM * HDIM + BB * NHD * HDIM;
        scan_kernel<<<(tot + 255) / 256, 256, 0, stream>>>(Cc, nc);
    }
    // 8. intra-chunk attention (q,k,v direct from proj) -> h fp32
    attn_kernel<<<NCHUNK, 256, 0, stream>>>(proj, lf, ic, Cc, nc, h);
    // 9. LN(o*h) + skip, * silu(rt) -> out1 planes
    ln_hid_split<<<NROW, 256, 0, stream>>>(h, o, xskip, rt, ln_hid_w, ln_hid_b, out1H, out1M);
    // 10. down (3-term) + residual x -> out (overwrites o scratch)
    gemm_sp<3,256><<<dim3(6, 64), 256, 0, stream>>>(out1H, out1M, nullptr, wdwnH, wdwnM, nullptr,
        down_b, x, out, nullptr, nullptr, D_IN, HID, 0);
}